// Round 8
// baseline (443.622 us; speedup 1.0000x reference)
//
#include <hip/hip_runtime.h>
#include <stdint.h>
#include <stddef.h>

#define BATCH 2
#define NELEM 131072           // anchors per batch (2^17)
#define OUT_NUM 2000

__device__ __forceinline__ float exp32cr(float x) { return (float)exp((double)x); }

// Decision "IoU > 0.7" bit-equivalent to numpy-f32 fl(inter/den) > 0.7f:
// multiply-compare with +-1e-4 relative guard band, exact __fdiv_rn in band.
__device__ __forceinline__ bool iou_gt(float by1, float bx1, float by2, float bx2,
                                       float cy1, float cx1, float cy2, float cx2) {
    float y1 = fmaxf(by1, cy1), x1 = fmaxf(bx1, cx1);
    float y2 = fminf(by2, cy2), x2 = fminf(bx2, cx2);
    float ih = __fsub_rn(y2, y1), iw = __fsub_rn(x2, x1);
    if (ih <= 0.0f || iw <= 0.0f) return false;
    float inter = __fmul_rn(ih, iw);
    float a1 = __fmul_rn(__fsub_rn(by2, by1), __fsub_rn(bx2, bx1));
    float a2 = __fmul_rn(__fsub_rn(cy2, cy1), __fsub_rn(cx2, cx1));
    float den = __fadd_rn(__fsub_rn(__fadd_rn(a1, a2), inter), 1e-8f);
    float rhs = __fmul_rn(0.7f, den);
    if (inter > __fmul_rn(rhs, 1.0001f)) return true;
    if (inter < __fmul_rn(rhs, 0.9999f)) return false;
    return __fdiv_rn(inter, den) > 0.7f;
}
__device__ __forceinline__ bool iou_gt4(float4 a, float4 c) {
    return iou_gt(a.x, a.y, a.z, a.w, c.x, c.y, c.z, c.w);
}

// NECESSARY condition for IoU>0.7 (same bound as round 7, verified absmax=0)
__device__ __forceinline__ bool maybe4(float4 A, float4 C) {
    float dy = fabsf((A.x + A.z) - (C.x + C.z));
    float dx = fabsf((A.y + A.w) - (C.y + C.w));
    float hs = (A.z - A.x) + (C.z - C.x);
    float ws = (A.w - A.y) + (C.w - C.y);
    return (dy < 0.19f * hs) && (dx < 0.19f * ws);
}

// f32 box decode mirroring numpy-f32 (no contraction, CR exp)
__device__ __forceinline__ void decode_f(const float* __restrict__ deltas,
                                         const float* __restrict__ anchors,
                                         size_t gi, float* bx) {
    float a0 = anchors[4 * gi], a1 = anchors[4 * gi + 1];
    float a2 = anchors[4 * gi + 2], a3 = anchors[4 * gi + 3];
    float h = __fsub_rn(a2, a0), w = __fsub_rn(a3, a1);
    float cy = __fmul_rn(__fadd_rn(a2, a0), 0.5f);
    float cx = __fmul_rn(__fadd_rn(a3, a1), 0.5f);
    float d0 = __fmul_rn(deltas[4 * gi], 0.1f);
    float d1 = __fmul_rn(deltas[4 * gi + 1], 0.1f);
    float d2 = __fmul_rn(deltas[4 * gi + 2], 0.2f);
    float d3 = __fmul_rn(deltas[4 * gi + 3], 0.2f);
    cy = __fadd_rn(cy, __fmul_rn(d0, h));
    cx = __fadd_rn(cx, __fmul_rn(d1, w));
    h = __fmul_rn(h, exp32cr(d2));
    w = __fmul_rn(w, exp32cr(d3));
    bx[0] = __fsub_rn(cy, __fmul_rn(h, 0.5f));
    bx[1] = __fsub_rn(cx, __fmul_rn(w, 0.5f));
    bx[2] = __fadd_rn(cy, __fmul_rn(h, 0.5f));
    bx[3] = __fadd_rn(cx, __fmul_rn(w, 0.5f));
}

__device__ __forceinline__ float score_f(const float* __restrict__ logits, size_t gi) {
    float l0 = logits[2 * gi], l1 = logits[2 * gi + 1];
    float m = fmaxf(l0, l1);
    float e0 = exp32cr(__fsub_rn(l0, m));
    float e1 = exp32cr(__fsub_rn(l1, m));
    return __fdiv_rn(e1, __fadd_rn(e0, e1));
}

// key = f32-score-bits << 17 | 17-bit ~idx ; also zeroes flag + state
__global__ __launch_bounds__(256) void prep_kernel(
    const float* __restrict__ logits, uint64_t* __restrict__ keys,
    uint32_t* __restrict__ flag, uint32_t* __restrict__ state) {
    int i = blockIdx.x * 256 + threadIdx.x;
    if (i == 0) *flag = 0;
    if (i < 32) state[i] = 0;
    if (i >= BATCH * NELEM) return;
    float s = score_f(logits, (size_t)i);
    uint32_t idx = (uint32_t)(i & (NELEM - 1));
    uint64_t key = 0;
    if (s > 0.05f)
        key = ((uint64_t)__float_as_uint(s) << 17) | ((~idx) & 0x1FFFFu);
    keys[i] = key;
}

// ---- bitonic sort (descending per batch) ------------------------------------
__global__ __launch_bounds__(1024) void bitonic_local_sort4(uint64_t* __restrict__ keys) {
    __shared__ uint64_t sh[4096];
    const int t = threadIdx.x;
    const size_t base = (size_t)blockIdx.x * 4096;
    for (int e = t; e < 4096; e += 1024) sh[e] = keys[base + e];
    __syncthreads();
    const int gb = (int)(base & (NELEM - 1));
    for (int k = 2; k <= 4096; k <<= 1) {
        for (int j = k >> 1; j >= 1; j >>= 1) {
            for (int pp = t; pp < 2048; pp += 1024) {
                int a = ((pp & ~(j - 1)) << 1) | (pp & (j - 1));
                bool ddd = (((gb + a) & k) == 0);
                uint64_t x = sh[a], y = sh[a + j];
                bool sw = ddd ? (x < y) : (x > y);
                if (sw) { sh[a] = y; sh[a + j] = x; }
            }
            __syncthreads();
        }
    }
    for (int e = t; e < 4096; e += 1024) keys[base + e] = sh[e];
}

__global__ __launch_bounds__(256) void bitonic_global_pass(uint64_t* __restrict__ keys,
                                                           int k, int j) {
    int tid = blockIdx.x * blockDim.x + threadIdx.x;
    const int half = NELEM / 2;
    int b = tid / half;
    int tt = tid - b * half;
    int a = ((tt & ~(j - 1)) << 1) | (tt & (j - 1));
    uint64_t* kb = keys + (size_t)b * NELEM;
    bool ddd = ((a & k) == 0);
    uint64_t x = kb[a], y = kb[a + j];
    bool sw = ddd ? (x < y) : (x > y);
    if (sw) { kb[a] = y; kb[a + j] = x; }
}

// fused two levels (j then j/2); direction uniform within quad (bits jh, j of
// x are zero by construction, so no carry into bit k).
__global__ __launch_bounds__(256) void bitonic_global_fused2(uint64_t* __restrict__ keys,
                                                             int k, int j) {
    int tid = blockIdx.x * 256 + threadIdx.x;
    const int q = NELEM / 4;
    int b = tid / q;
    int tt = tid - b * q;
    int jh = j >> 1;
    int x = ((tt & ~(jh - 1)) << 2) | (tt & (jh - 1));
    uint64_t* kb = keys + (size_t)b * NELEM;
    bool ddd = ((x & k) == 0);
    uint64_t e0 = kb[x], e1 = kb[x + jh], e2 = kb[x + j], e3 = kb[x + j + jh];
    uint64_t tmp;
#define CMPEX(A, B) { bool sw = ddd ? (A < B) : (A > B); if (sw) { tmp = A; A = B; B = tmp; } }
    CMPEX(e0, e2) CMPEX(e1, e3)
    CMPEX(e0, e1) CMPEX(e2, e3)
#undef CMPEX
    kb[x] = e0; kb[x + jh] = e1; kb[x + j] = e2; kb[x + j + jh] = e3;
}

// 8192-element local merge: absorbs all j<=4096 levels of a merge stage
__global__ __launch_bounds__(1024) void bitonic_local_merge8(uint64_t* __restrict__ keys,
                                                             int k) {
    __shared__ uint64_t sh[8192];
    const int t = threadIdx.x;
    const size_t base = (size_t)blockIdx.x * 8192;
    for (int e = t; e < 8192; e += 1024) sh[e] = keys[base + e];
    __syncthreads();
    const bool ddd = (((int)(base & (NELEM - 1)) & k) == 0);  // uniform, k >= 8192
    for (int j = 4096; j >= 1; j >>= 1) {
        for (int pp = t; pp < 4096; pp += 1024) {
            int a = ((pp & ~(j - 1)) << 1) | (pp & (j - 1));
            uint64_t x = sh[a], y = sh[a + j];
            bool sw = ddd ? (x < y) : (x > y);
            if (sw) { sh[a] = y; sh[a + j] = x; }
        }
        __syncthreads();
    }
    for (int e = t; e < 8192; e += 1024) keys[base + e] = sh[e];
}

// canary A: verify per-batch non-increasing order
__global__ __launch_bounds__(256) void sort_check(const uint64_t* __restrict__ keys,
                                                  uint32_t* __restrict__ flag) {
    int i = blockIdx.x * 256 + threadIdx.x;
    if (i >= BATCH * NELEM) return;
    uint32_t q = (uint32_t)i & (NELEM - 1);
    if (q != NELEM - 1) {
        if (keys[i] < keys[i + 1]) atomicOr(flag, 1u);
    }
}

// ---- packed candidate records for top-M: [y1 x1 y2 x2 | score l0 l1 valid] --
__global__ __launch_bounds__(256) void records_kernel(
    const uint64_t* __restrict__ keys, const float* __restrict__ deltas,
    const float* __restrict__ anchors, const float* __restrict__ logits,
    float* __restrict__ records, int M) {
    int g = blockIdx.x * 256 + threadIdx.x;
    if (g >= BATCH * M) return;
    int b = g / M, r = g - b * M;
    uint64_t key = keys[(size_t)b * NELEM + r];
    float4 r0, r1;
    if (key != 0) {
        uint32_t idx = (uint32_t)((~key) & 0x1FFFFu);
        size_t gi = (size_t)b * NELEM + idx;
        float bx[4];
        decode_f(deltas, anchors, gi, bx);
        r0 = make_float4(bx[0], bx[1], bx[2], bx[3]);
        r1 = make_float4(score_f(logits, gi), logits[2 * gi], logits[2 * gi + 1], 1.0f);
    } else {
        r0 = make_float4(0.f, 0.f, 0.f, 0.f);
        r1 = make_float4(0.f, 0.f, 0.f, 0.f);
    }
    float4* rp = (float4*)records;
    rp[(size_t)g * 2] = r0;
    rp[(size_t)g * 2 + 1] = r1;
}

// ---- backward kill masks incl. diagonal tile --------------------------------
__global__ __launch_bounds__(64) void mask_kernel(const float* __restrict__ records,
                                                  uint64_t* __restrict__ masks, int M) {
    int ti = blockIdx.x, tj = blockIdx.y, b = blockIdx.z;
    if (tj > ti) return;
    int t = threadIdx.x;
    __shared__ float4 jb[64];
    __shared__ int jv[64];
    const float4* rp = (const float4*)records;
    {
        float4 rj  = rp[((size_t)b * M + (size_t)tj * 64 + t) * 2];
        float4 rj1 = rp[((size_t)b * M + (size_t)tj * 64 + t) * 2 + 1];
        jb[t] = rj;
        jv[t] = (rj1.w != 0.f);
    }
    float4 ri  = rp[((size_t)b * M + (size_t)ti * 64 + t) * 2];
    float4 ri1 = rp[((size_t)b * M + (size_t)ti * 64 + t) * 2 + 1];
    bool iv = (ri1.w != 0.f);
    __syncthreads();
    uint64_t word = 0;
    if (iv) {
        for (int jj = 0; jj < 64; ++jj) {
            bool earlier = (tj < ti) || (jj < t);
            if (earlier && jv[jj] && maybe4(jb[jj], ri) && iou_gt4(jb[jj], ri))
                word |= 1ull << jj;
        }
    }
    masks[((size_t)b * M + (size_t)ti * 64 + t) * (size_t)(M >> 6) + tj] = word;
}

// ---- G1: pipelined bitset greedy walk over top-M ----------------------------
__global__ __launch_bounds__(512) void nms_walk(
    const uint64_t* __restrict__ keys, const float* __restrict__ records,
    const uint64_t* __restrict__ masks, float4* __restrict__ accbox,
    uint32_t* __restrict__ state, float* __restrict__ out, int M) {
    const int b = blockIdx.x;
    const int t = threadIdx.x;
    const int c = t >> 3, wl = t & 7;
    const int Wm = M >> 6;
    const uint64_t* browbase = masks + (size_t)b * M * (size_t)Wm;

    __shared__ uint64_t accset[128];
    __shared__ uint64_t backW[64];
    __shared__ uint8_t kflag[64];
    __shared__ uint32_t s_state[5];

    uint64_t pref[16];
#pragma unroll
    for (int u = 0; u < 16; ++u) pref[u] = 0;
    uint64_t diag = 0, keyCur = 0;
    float4 rec0 = make_float4(0.f, 0.f, 0.f, 0.f);
    float4 rec1 = make_float4(0.f, 0.f, 0.f, 0.f);
    float4 nrec0 = rec0, nrec1 = rec1;

    // prologue: chunk 0
    if (t < 64) keyCur = keys[(size_t)b * NELEM + t];
    if (wl == 1) diag = browbase[(size_t)c * Wm + 0];
    if (t >= 448) {
        const float4* rp = (const float4*)records + ((size_t)b * M + (t - 448)) * 2;
        rec0 = rp[0]; rec1 = rp[1];
    }
    for (int w = t; w < 128; w += 512) accset[w] = 0;
    if (t < 64) kflag[t] = 0;
    __syncthreads();

    int n_acc = 0, done = 0;
    for (int ci = 0; ci < Wm && !done; ++ci) {
        const int p = ci << 6;
        // B: pure register/LDS AND over prior chunks
        uint64_t o = 0;
#pragma unroll
        for (int u = 0; u < 16; ++u) {
            int w = wl + (u << 3);
            if (w < ci) o |= pref[u] & accset[w];
        }
        if (wl == 1) backW[c] = diag;
        {
            uint32_t lo = (uint32_t)o, hi = (uint32_t)(o >> 32);
            lo |= __shfl_xor((int)lo, 1); hi |= __shfl_xor((int)hi, 1);
            lo |= __shfl_xor((int)lo, 2); hi |= __shfl_xor((int)hi, 2);
            lo |= __shfl_xor((int)lo, 4); hi |= __shfl_xor((int)hi, 4);
            if (wl == 0) kflag[c] = ((lo | hi) != 0) ? 1 : 0;
        }
        __syncthreads();

        // D: wave0 validity+scan; all waves prefetch chunk ci+1 into regs
        uint64_t vmcur = 0;
        if (t < 64) vmcur = __ballot(keyCur != 0);
        if (ci + 1 < Wm) {
            const uint64_t* rowN = browbase + (size_t)((ci + 1) * 64 + c) * Wm;
#pragma unroll
            for (int u = 0; u < 16; ++u) {
                int w = wl + (u << 3);
                if (w <= ci) pref[u] = rowN[w];
            }
            if (wl == 1) diag = rowN[ci + 1];
            if (t < 64) keyCur = keys[(size_t)b * NELEM + p + 64 + t];
            if (t >= 448) {
                const float4* rp = (const float4*)records +
                                   ((size_t)b * M + p + 64 + (t - 448)) * 2;
                nrec0 = rp[0]; nrec1 = rp[1];
            }
        }
        if (t < 64) {
            uint64_t killed = __ballot(kflag[t] != 0);
            uint64_t bw = backW[t];
            uint64_t todo = vmcur & ~killed;
            uint64_t am = 0;
            int n = n_acc;
            int dn = (vmcur != ~0ull);
            while (todo) {
                int cb = __builtin_ctzll(todo);
                todo &= todo - 1;
                am |= 1ull << cb;
                ++n;
                if (n == OUT_NUM) { dn = 1; break; }
                uint64_t kb = __ballot(((bw >> cb) & 1) != 0);
                todo &= ~kb;
            }
            if (t == 0) {
                s_state[0] = (uint32_t)n_acc;
                s_state[1] = (uint32_t)n;
                s_state[2] = (uint32_t)dn;
                s_state[3] = (uint32_t)am;
                s_state[4] = (uint32_t)(am >> 32);
                accset[ci] = am;
            }
        }
        __syncthreads();
        int r0 = (int)s_state[0];
        n_acc = (int)s_state[1];
        done = (int)s_state[2];
        uint64_t am = ((uint64_t)s_state[4] << 32) | s_state[3];

        // E: wave 7 writes outputs from CURRENT chunk's prefetched records
        const int l = t - 448;
        if (l >= 0 && ((am >> l) & 1)) {
            int row = r0 + (int)__popcll(am & ((1ull << l) - 1ull));
            accbox[(size_t)b * OUT_NUM + row] = rec0;
            float* ob = out + ((size_t)b * OUT_NUM + row) * 5;
            ob[0] = rec0.x; ob[1] = rec0.y; ob[2] = rec0.z; ob[3] = rec0.w; ob[4] = 1.0f;
            float* os = out + (size_t)BATCH * OUT_NUM * 5 + ((size_t)b * OUT_NUM + row) * 2;
            os[0] = rec1.x; os[1] = 1.0f;
            float* ol = out + (size_t)BATCH * OUT_NUM * 7 + ((size_t)b * OUT_NUM + row) * 3;
            ol[0] = rec1.y; ol[1] = rec1.z; ol[2] = 1.0f;
        }
        rec0 = nrec0; rec1 = nrec1;   // commit next-chunk records after E
    }
    if (t == 0) {
        state[b * 16] = (uint32_t)n_acc;
        state[b * 16 + 1] = (uint32_t)done;
    }
}

// ---- G2: tail beyond M, decode overlapped with IoU, SoA prefilter -----------
__global__ void nms_tail(
    const uint64_t* __restrict__ keys, const float* __restrict__ deltas,
    const float* __restrict__ logits, const float* __restrict__ anchors,
    const float4* __restrict__ accbox, const uint32_t* __restrict__ state,
    float* __restrict__ out, int Mend) {
    const int b = blockIdx.x;
    const int t = threadIdx.x;
    const int BD = blockDim.x;
    const int NW = BD >> 6;
    const int wid = t >> 6;

    __shared__ float4 aF4[OUT_NUM];
    __shared__ float4 aS4[OUT_NUM];
    __shared__ float4 cbox[2][64], cmeta[2][64];
    __shared__ uint32_t transL[64], transH[64];
    __shared__ uint32_t killedL, killedH;
    __shared__ uint32_t s_state[5];

    if (t == 0) {
        killedL = 0; killedH = 0;
        s_state[0] = state[b * 16];
        s_state[1] = state[b * 16 + 1];
    }
    if (t < 64) { transL[t] = 0; transH[t] = 0; }
    __syncthreads();
    int n_acc = (int)s_state[0];
    int done = (int)s_state[1];
    for (int r = t; r < n_acc; r += BD) {
        float4 ab = accbox[(size_t)b * OUT_NUM + r];
        aF4[r] = ab;
        aS4[r] = make_float4(ab.x + ab.z, ab.y + ab.w, ab.z - ab.x, ab.w - ab.y);
    }
    if (t < 64) {  // prologue decode chunk 0
        uint64_t key = keys[(size_t)b * NELEM + Mend + t];
        float4 bx4 = make_float4(0.f, 0.f, 0.f, 0.f);
        float4 mt = make_float4(0.f, 0.f, 0.f, 0.f);
        if (key != 0) {
            uint32_t idx = (uint32_t)((~key) & 0x1FFFFu);
            size_t gi = (size_t)b * NELEM + idx;
            float bx[4];
            decode_f(deltas, anchors, gi, bx);
            bx4 = make_float4(bx[0], bx[1], bx[2], bx[3]);
            mt = make_float4(score_f(logits, gi), logits[2 * gi],
                             logits[2 * gi + 1], 1.0f);
        }
        cbox[0][t] = bx4; cmeta[0][t] = mt;
    }
    uint64_t keyN = 0;
    if (wid == 1 && Mend + 128 <= NELEM)
        keyN = keys[(size_t)b * NELEM + Mend + 64 + (t - 64)];
    __syncthreads();

    int bi = 0;
    for (int p = Mend; p < NELEM && !done; p += 64, bi ^= 1) {
        const bool havenext = (p + 128) <= NELEM;
        if (wid == 1) {
            if (havenext) {
                const int tw = t - 64;
                float4 bx4 = make_float4(0.f, 0.f, 0.f, 0.f);
                float4 mt = make_float4(0.f, 0.f, 0.f, 0.f);
                if (keyN != 0) {
                    uint32_t idx = (uint32_t)((~keyN) & 0x1FFFFu);
                    size_t gi = (size_t)b * NELEM + idx;
                    float bx[4];
                    decode_f(deltas, anchors, gi, bx);
                    bx4 = make_float4(bx[0], bx[1], bx[2], bx[3]);
                    mt = make_float4(score_f(logits, gi), logits[2 * gi],
                                     logits[2 * gi + 1], 1.0f);
                }
                cbox[bi ^ 1][tw] = bx4; cmeta[bi ^ 1][tw] = mt;
                keyN = 0;
                if (p + 192 <= NELEM)
                    keyN = keys[(size_t)b * NELEM + p + 128 + tw];
            }
        } else {
            const int cc = t & 63;
            float4 cb = cbox[bi][cc];
            bool valid = (cmeta[bi][cc].w != 0.f);
            float csy = cb.x + cb.z, csx = cb.y + cb.w;
            float chh = cb.z - cb.x, cww = cb.w - cb.y;
            bool k = false;
            if (valid) {
                int wv = wid - (wid > 1 ? 1 : 0);
                for (int a = wv; a < n_acc; a += NW - 1) {
                    float4 as = aS4[a];
                    if (fabsf(as.x - csy) < 0.19f * (as.z + chh) &&
                        fabsf(as.y - csx) < 0.19f * (as.w + cww)) {
                        if (iou_gt4(aF4[a], cb)) { k = true; break; }
                    }
                }
            }
            if (k) {
                if (cc < 32) atomicOr(&killedL, 1u << cc);
                else atomicOr(&killedH, 1u << (cc - 32));
            }
        }
        for (int pid = t; pid < 64 * 64; pid += BD) {
            int c0 = pid >> 6, c1 = pid & 63;
            if (c1 > c0 && cmeta[bi][c0].w != 0.f && cmeta[bi][c1].w != 0.f) {
                if (maybe4(cbox[bi][c0], cbox[bi][c1]) &&
                    iou_gt4(cbox[bi][c0], cbox[bi][c1])) {
                    if (c1 < 32) atomicOr(&transL[c0], 1u << c1);
                    else atomicOr(&transH[c0], 1u << (c1 - 32));
                }
            }
        }
        __syncthreads();

        if (t < 64) {
            uint32_t mtL = transL[t], mtH = transH[t];
            uint64_t vm = __ballot(cmeta[bi][t].w != 0.f);
            uint64_t killed = ((uint64_t)killedH << 32) | killedL;
            uint64_t todo = vm & ~killed;
            uint64_t am = 0;
            int n = n_acc;
            int dn = (vm != ~0ull);
            while (todo) {
                int cb2 = __builtin_ctzll(todo);
                todo &= todo - 1;
                am |= 1ull << cb2;
                ++n;
                if (n == OUT_NUM) { dn = 1; break; }
                uint32_t tl = (uint32_t)__shfl((int)mtL, cb2);
                uint32_t th = (uint32_t)__shfl((int)mtH, cb2);
                todo &= ~(((uint64_t)th << 32) | tl);
            }
            if (t == 0) {
                s_state[0] = (uint32_t)n_acc;
                s_state[1] = (uint32_t)n;
                s_state[2] = (uint32_t)dn;
                s_state[3] = (uint32_t)am;
                s_state[4] = (uint32_t)(am >> 32);
                killedL = 0; killedH = 0;
            }
        }
        __syncthreads();
        int r0 = (int)s_state[0];
        n_acc = (int)s_state[1];
        done = (int)s_state[2];
        uint64_t am = ((uint64_t)s_state[4] << 32) | s_state[3];

        if (t < 64) {
            if ((am >> t) & 1) {
                int row = r0 + (int)__popcll(am & ((1ull << t) - 1ull));
                float4 cb = cbox[bi][t];
                float4 cm = cmeta[bi][t];
                aF4[row] = cb;
                aS4[row] = make_float4(cb.x + cb.z, cb.y + cb.w,
                                       cb.z - cb.x, cb.w - cb.y);
                float* ob = out + ((size_t)b * OUT_NUM + row) * 5;
                ob[0] = cb.x; ob[1] = cb.y; ob[2] = cb.z; ob[3] = cb.w; ob[4] = 1.0f;
                float* os = out + (size_t)BATCH * OUT_NUM * 5 +
                            ((size_t)b * OUT_NUM + row) * 2;
                os[0] = cm.x; os[1] = 1.0f;
                float* ol = out + (size_t)BATCH * OUT_NUM * 7 +
                            ((size_t)b * OUT_NUM + row) * 3;
                ol[0] = cm.y; ol[1] = cm.z; ol[2] = 1.0f;
            }
            transL[t] = 0; transH[t] = 0;
        }
        __syncthreads();
    }

    for (int r = n_acc + t; r < OUT_NUM; r += BD) {
        float* ob = out + ((size_t)b * OUT_NUM + r) * 5;
        ob[0] = 0.f; ob[1] = 0.f; ob[2] = 0.f; ob[3] = 0.f; ob[4] = 0.f;
        float* os = out + (size_t)BATCH * OUT_NUM * 5 + ((size_t)b * OUT_NUM + r) * 2;
        os[0] = 0.f; os[1] = 0.f;
        float* ol = out + (size_t)BATCH * OUT_NUM * 7 + ((size_t)b * OUT_NUM + r) * 3;
        ol[0] = 0.f; ol[1] = 0.f; ol[2] = 0.f;
    }
    if (t == 0 && n_acc < OUT_NUM) out[0] = 2.0e5f;  // canary B
}

__global__ void canary_kernel(const uint32_t* __restrict__ flag, float* __restrict__ out,
                              int code) {
    if (code) { out[0] = 3.0e5f; return; }
    if (*flag) out[0] = 1.0e5f;
}

extern "C" void kernel_launch(void* const* d_in, const int* in_sizes, int n_in,
                              void* d_out, int out_size, void* d_ws, size_t ws_size,
                              hipStream_t stream) {
    const float* deltas  = (const float*)d_in[0];
    const float* logits  = (const float*)d_in[1];
    const float* anchors = (const float*)d_in[2];
    float* out = (float*)d_out;

    const size_t keysB = (size_t)BATCH * NELEM * 8;
    const size_t flagOff = keysB;
    const size_t stateOff = keysB + 256;
    const size_t accOff = keysB + 512;
    const size_t recOff = keysB + 65536;
    if (ws_size < recOff) {
        canary_kernel<<<1, 1, 0, stream>>>((const uint32_t*)d_ws, out, 1);
        return;
    }
    int M = 0, g2bs = 832;
    const int tiers[3] = {8192, 4096, 2048};
    const int tbs[3]   = {1024, 960, 896};
    for (int i = 0; i < 3; ++i) {
        int cand = tiers[i];
        size_t need = recOff + (size_t)BATCH * cand * 32 +
                      (size_t)BATCH * cand * (cand / 8);
        if (ws_size >= need) { M = cand; g2bs = tbs[i]; break; }
    }

    uint64_t* keys = (uint64_t*)d_ws;
    uint32_t* flag = (uint32_t*)((char*)d_ws + flagOff);
    uint32_t* state = (uint32_t*)((char*)d_ws + stateOff);
    float4* accbox = (float4*)((char*)d_ws + accOff);
    float* records = (float*)((char*)d_ws + recOff);
    uint64_t* masks = (uint64_t*)((char*)d_ws + recOff + (size_t)BATCH * M * 32);

    prep_kernel<<<(BATCH * NELEM) / 256, 256, 0, stream>>>(logits, keys, flag, state);

    bitonic_local_sort4<<<BATCH * NELEM / 4096, 1024, 0, stream>>>(keys);
    bitonic_local_merge8<<<BATCH * NELEM / 8192, 1024, 0, stream>>>(keys, 8192);
    bitonic_global_pass<<<(BATCH * NELEM / 2) / 256, 256, 0, stream>>>(keys, 16384, 8192);
    bitonic_local_merge8<<<BATCH * NELEM / 8192, 1024, 0, stream>>>(keys, 16384);
    bitonic_global_fused2<<<(BATCH * NELEM / 4) / 256, 256, 0, stream>>>(keys, 32768, 16384);
    bitonic_local_merge8<<<BATCH * NELEM / 8192, 1024, 0, stream>>>(keys, 32768);
    bitonic_global_fused2<<<(BATCH * NELEM / 4) / 256, 256, 0, stream>>>(keys, 65536, 32768);
    bitonic_global_pass<<<(BATCH * NELEM / 2) / 256, 256, 0, stream>>>(keys, 65536, 8192);
    bitonic_local_merge8<<<BATCH * NELEM / 8192, 1024, 0, stream>>>(keys, 65536);
    bitonic_global_fused2<<<(BATCH * NELEM / 4) / 256, 256, 0, stream>>>(keys, 131072, 65536);
    bitonic_global_fused2<<<(BATCH * NELEM / 4) / 256, 256, 0, stream>>>(keys, 131072, 16384);
    bitonic_local_merge8<<<BATCH * NELEM / 8192, 1024, 0, stream>>>(keys, 131072);

    sort_check<<<(BATCH * NELEM) / 256, 256, 0, stream>>>(keys, flag);
    if (M > 0) {
        records_kernel<<<(BATCH * M) / 256, 256, 0, stream>>>(keys, deltas, anchors,
                                                              logits, records, M);
        dim3 mg(M / 64, M / 64, BATCH);
        mask_kernel<<<mg, 64, 0, stream>>>(records, masks, M);
        nms_walk<<<BATCH, 512, 0, stream>>>(keys, records, masks, accbox, state, out, M);
    }
    nms_tail<<<BATCH, g2bs, 0, stream>>>(keys, deltas, logits, anchors, accbox,
                                         state, out, M);
    canary_kernel<<<1, 1, 0, stream>>>(flag, out, 0);
}